// Round 1
// 381.668 us; speedup vs baseline: 1.8286x; 1.8286x over previous
//
#include <hip/hip_runtime.h>

#define BB   32
#define EE   256
#define HH   64
#define WW   64
#define HIDN 256

typedef short bf16x8 __attribute__((ext_vector_type(8)));   // 8 bf16 = 4 VGPR (MFMA A/B frag)
typedef float f32x4  __attribute__((ext_vector_type(4)));   // MFMA C/D frag

__device__ __forceinline__ float ubf(unsigned short u) {
  return __uint_as_float(((unsigned)u) << 16);
}
__device__ __forceinline__ unsigned f2bf(float f) {
  unsigned u = __float_as_uint(f);
  u += 0x7fffu + ((u >> 16) & 1u);   // round-to-nearest-even
  return u >> 16;
}

// Transposed x tile in LDS: element (w, c) of [64 w][256 c] bf16.
// 16B slot (8 bf16) index within a row is XORed with (w&7) so that
// fixed-c-column accesses across w spread over 8 bank-groups (the b128
// conflict-free optimum). Bijective per row (XOR permutes low 3 slot bits).
__device__ __forceinline__ int xt_idx(int w, int c) {
  return (w << 8) + ((((c >> 3) ^ (w & 7)) << 3) | (c & 7));
}

// ---------------- prep kernel: split Wv / Wout into hi/lo bf16, fragment-major ----
// Layout: frag index ((mt*8 + ks)*2 + hl)*64 + lane, each frag = 8 bf16 (16B).
// Lane holds W[m = mt*16 + (lane&15)][k = ks*32 + (lane>>4)*8 + i], i=0..7
// -> A-fragment load in the GEMM is ONE coalesced global_load_dwordx4 per lane.
__global__ __launch_bounds__(256) void prep_weights(
    const float* __restrict__ Wqkv, const float* __restrict__ Wout,
    unsigned short* __restrict__ ws)
{
  const int t = blockIdx.x * 256 + threadIdx.x;   // 16384 threads total
  const int which = t >> 13;                      // 0 = Wv (qkv rows 257..512), 1 = Wout
  const int r = t & 8191;
  const int m = r >> 5, k8 = r & 31, k0 = k8 * 8;
  const float* src = which ? (Wout + m * HIDN + k0)
                           : (Wqkv + (1 + HIDN + m) * EE + k0);
  unsigned short* dst = ws + which * 131072;      // 256 KB (shorts) per matrix
  float4 a = *(const float4*)src;
  float4 bq = *(const float4*)(src + 4);
  float v[8] = {a.x, a.y, a.z, a.w, bq.x, bq.y, bq.z, bq.w};
  const int mt = m >> 4, ks = k8 >> 2, lane = (m & 15) + ((k8 & 3) << 4);
  const int base = ((mt * 8 + ks) * 2) * 64 * 8 + lane * 8;   // hi block; lo at +512
  __align__(16) unsigned short hs[8], ls[8];
  #pragma unroll
  for (int i = 0; i < 8; ++i) {
    unsigned h = f2bf(v[i]);
    hs[i] = (unsigned short)h;
    ls[i] = (unsigned short)f2bf(v[i] - ubf((unsigned short)h));
  }
  *(uint4*)&dst[base]       = *(const uint4*)hs;
  *(uint4*)&dst[base + 512] = *(const uint4*)ls;
}

// ---------------- MFMA GEMM: C[256 m][64 w] = W[256 m][256 k] * Xt[k][w] ----------
// 4 waves, wave wid owns m in [wid*64, wid*64+64) as 4 mtiles x 4 ntiles of 16x16.
// 2-way bf16 split on both operands: acc += Ah*Bh + Ah*Bl + Al*Bh  (drop lo*lo,
// rel err ~2^-18). A frags stream from the prepped global layout (L2-hot,
// coalesced); B frags are ds_read_b128 from the swizzled LDS tile. NO barriers.
__device__ __forceinline__ void mfma_gemm(
    const bf16x8* __restrict__ Wp,
    const unsigned short* __restrict__ Xhp,
    const unsigned short* __restrict__ Xlp,
    const int wid, const int lane, f32x4 acc[4][4])
{
  const int l15 = lane & 15;
  const int kb  = (lane >> 4) * 8;
  #pragma unroll
  for (int ks = 0; ks < 8; ++ks) {
    bf16x8 bhf[4], blf[4];
    #pragma unroll
    for (int ni = 0; ni < 4; ++ni) {
      const int w  = ni * 16 + l15;       // B frag: n = lane&15, k = ks*32 + (lane>>4)*8 + i
      const int c0 = ks * 32 + kb;
      bhf[ni] = *(const bf16x8*)&Xhp[xt_idx(w, c0)];
      blf[ni] = *(const bf16x8*)&Xlp[xt_idx(w, c0)];
    }
    bf16x8 ahf[4], alf[4];
    #pragma unroll
    for (int mi = 0; mi < 4; ++mi) {
      const int fb = ((wid * 4 + mi) * 8 + ks) * 2;
      ahf[mi] = Wp[fb * 64 + lane];
      alf[mi] = Wp[(fb + 1) * 64 + lane];
    }
    #pragma unroll
    for (int mi = 0; mi < 4; ++mi) {
      #pragma unroll
      for (int ni = 0; ni < 4; ++ni) {
        acc[mi][ni] = __builtin_amdgcn_mfma_f32_16x16x32_bf16(ahf[mi], bhf[ni], acc[mi][ni], 0, 0, 0);
        acc[mi][ni] = __builtin_amdgcn_mfma_f32_16x16x32_bf16(ahf[mi], blf[ni], acc[mi][ni], 0, 0, 0);
        acc[mi][ni] = __builtin_amdgcn_mfma_f32_16x16x32_bf16(alf[mi], bhf[ni], acc[mi][ni], 0, 0, 0);
      }
    }
  }
}

// One workgroup = one (b,h) slice, 256 threads = 4 waves.
// LDS 70.9 KB -> 2 blocks/CU; launch_bounds(256,2) caps VGPR at 256 (2 waves/SIMD).
__global__ __launch_bounds__(256, 2) void sep_attn_mfma(
    const float* __restrict__ x, const float* __restrict__ Wqkv,
    const float* __restrict__ bqkv, const float* __restrict__ bout,
    float* __restrict__ out, const unsigned short* __restrict__ wsp)
{
  __shared__ __align__(16) unsigned short Xh[64 * 256];   // 32 KB, x-hi then gated-hi
  __shared__ __align__(16) unsigned short Xl[64 * 256];   // 32 KB, x-lo then gated-lo
  __shared__ __align__(16) float qpart[256];
  __shared__ __align__(16) float ss[64];
  __shared__ __align__(16) float xbar_s[EE];
  __shared__ __align__(16) float cvs[EE];
  __shared__ __align__(16) float sbv[EE];      // value bias  bqkv[257..512]
  __shared__ __align__(16) float sbout[EE];    // output bias

  const int tid  = threadIdx.x;
  const int lane = tid & 63;
  const int wid  = tid >> 6;
  const int bh = blockIdx.x;
  const int b  = bh >> 6;
  const int h  = bh & 63;
  const int gbase = (b * EE) * 4096 + h * 64;   // x[b,c,h,w] = x[gbase + c*4096 + w]

  // ---- P0: stage x slice -> LDS transposed bf16 hi/lo (+ bias staging) ----
  {
    const int c = tid;
    const float* xp = x + gbase + c * 4096;
    sbv[tid]   = bqkv[1 + HIDN + tid];
    sbout[tid] = bout[tid];
    #pragma unroll
    for (int f = 0; f < 16; ++f) {
      float4 xv = *(const float4*)&xp[f * 4];
      float vv[4] = {xv.x, xv.y, xv.z, xv.w};
      #pragma unroll
      for (int j = 0; j < 4; ++j) {
        const int w = f * 4 + j;
        unsigned hu = f2bf(vv[j]);
        Xh[xt_idx(w, c)] = (unsigned short)hu;
        Xl[xt_idx(w, c)] = (unsigned short)f2bf(vv[j] - ubf((unsigned short)hu));
      }
    }
  }
  __syncthreads();

  // ---- P1: query partials from LDS (x ~= hi+lo, rel err 2^-18) ----
  {
    const int w = tid & 63, cg = tid >> 6;     // cg wave-uniform -> Wq loads scalar
    const float* wq = Wqkv + cg * 64;
    float q = 0.f;
    #pragma unroll
    for (int f = 0; f < 8; ++f) {
      const int c0 = cg * 64 + f * 8;
      bf16x8 hv = *(const bf16x8*)&Xh[xt_idx(w, c0)];
      bf16x8 lv = *(const bf16x8*)&Xl[xt_idx(w, c0)];
      float4 wa = *(const float4*)&wq[f * 8];
      float4 wb = *(const float4*)&wq[f * 8 + 4];
      float wf[8] = {wa.x, wa.y, wa.z, wa.w, wb.x, wb.y, wb.z, wb.w};
      #pragma unroll
      for (int e = 0; e < 8; ++e)
        q = fmaf(wf[e], ubf((unsigned short)hv[e]) + ubf((unsigned short)lv[e]), q);
    }
    qpart[tid] = q;                            // tid == cg*64 + w
  }
  __syncthreads();

  // ---- P2: softmax over the 64 w positions (one wave) ----
  if (tid < 64) {
    float q = qpart[tid] + qpart[64 + tid] + qpart[128 + tid] + qpart[192 + tid] + bqkv[0];
    float m = q;
    #pragma unroll
    for (int off = 32; off; off >>= 1) m = fmaxf(m, __shfl_xor(m, off));
    float e = expf(q - m);
    float s = e;
    #pragma unroll
    for (int off = 32; off; off >>= 1) s += __shfl_xor(s, off);
    ss[tid] = e / s;
  }
  __syncthreads();

  // ---- P3: xbar[c] = sum_w score[w] * x[b,c,h,w]  (global re-read, L2-hot) ----
  {
    const int c = tid;
    float a = 0.f;
    #pragma unroll
    for (int f = 0; f < 16; ++f) {
      float4 sv = *(const float4*)&ss[f * 4];
      float4 xv = *(const float4*)&x[gbase + c * 4096 + f * 4];
      a += sv.x * xv.x + sv.y * xv.y + sv.z * xv.z + sv.w * xv.w;
    }
    xbar_s[c] = a;
  }
  __syncthreads();

  // ---- P4: cv[c] = Wk_row(c) . xbar + bk[c]  (key GEMM collapsed) ----
  {
    const int c = tid;
    const float* wk = Wqkv + (1 + c) * EE;
    float a = 0.f;
    #pragma unroll 8
    for (int f = 0; f < 64; ++f) {
      float4 wv = *(const float4*)&wk[f * 4];
      float4 xb = *(const float4*)&xbar_s[f * 4];
      a += wv.x * xb.x + wv.y * xb.y + wv.z * xb.z + wv.w * xb.w;
    }
    cvs[c] = a + bqkv[1 + c];
    // visibility to the gating phase is guaranteed by the post-GEMM1 barrier
  }

  // ---- GEMM1: value = Wv * x  (barrier-free K-loop, MFMA bf16 2-way split) ----
  f32x4 acc[4][4];
  #pragma unroll
  for (int mi = 0; mi < 4; ++mi)
    #pragma unroll
    for (int ni = 0; ni < 4; ++ni) {
      acc[mi][ni][0] = 0.f; acc[mi][ni][1] = 0.f;
      acc[mi][ni][2] = 0.f; acc[mi][ni][3] = 0.f;
    }
  mfma_gemm((const bf16x8*)wsp, Xh, Xl, wid, lane, acc);
  __syncthreads();   // all waves done reading Xt; cvs now visible

  // ---- Gate: relu(value + bv) * cv, split hi/lo, write transposed into LDS ----
  // D-frag rows are 4 CONSECUTIVE hid channels per lane -> one b64 store per frag.
  {
    const int l15 = lane & 15, l4 = lane >> 4;
    #pragma unroll
    for (int mi = 0; mi < 4; ++mi) {
      const int c0 = (wid * 4 + mi) * 16 + l4 * 4;
      float4 cv4 = *(const float4*)&cvs[c0];
      float4 bv4 = *(const float4*)&sbv[c0];
      float cvv[4] = {cv4.x, cv4.y, cv4.z, cv4.w};
      float bvv[4] = {bv4.x, bv4.y, bv4.z, bv4.w};
      #pragma unroll
      for (int ni = 0; ni < 4; ++ni) {
        const int w = ni * 16 + l15;
        unsigned hs[4], lsv[4];
        #pragma unroll
        for (int rg = 0; rg < 4; ++rg) {
          float g = fmaxf(acc[mi][ni][rg] + bvv[rg], 0.f) * cvv[rg];
          unsigned hu = f2bf(g);
          hs[rg]  = hu;
          lsv[rg] = f2bf(g - ubf((unsigned short)hu));
        }
        uint2 uh, ul;
        uh.x = hs[0]  | (hs[1]  << 16); uh.y = hs[2]  | (hs[3]  << 16);
        ul.x = lsv[0] | (lsv[1] << 16); ul.y = lsv[2] | (lsv[3] << 16);
        *(uint2*)&Xh[xt_idx(w, c0)] = uh;   // slot-aligned 8B
        *(uint2*)&Xl[xt_idx(w, c0)] = ul;
      }
    }
  }
  __syncthreads();

  // ---- GEMM2: out = Wout * gated ----
  #pragma unroll
  for (int mi = 0; mi < 4; ++mi)
    #pragma unroll
    for (int ni = 0; ni < 4; ++ni) {
      acc[mi][ni][0] = 0.f; acc[mi][ni][1] = 0.f;
      acc[mi][ni][2] = 0.f; acc[mi][ni][3] = 0.f;
    }
  mfma_gemm((const bf16x8*)(wsp + 131072), Xh, Xl, wid, lane, acc);

  // ---- Epilogue: bias + store (4x 64B segments per instr -> coalesced) ----
  {
    const int l15 = lane & 15, l4 = lane >> 4;
    #pragma unroll
    for (int mi = 0; mi < 4; ++mi) {
      const int e0 = (wid * 4 + mi) * 16 + l4 * 4;
      float4 bo4 = *(const float4*)&sbout[e0];
      float bov[4] = {bo4.x, bo4.y, bo4.z, bo4.w};
      #pragma unroll
      for (int ni = 0; ni < 4; ++ni) {
        const int w = ni * 16 + l15;
        #pragma unroll
        for (int rg = 0; rg < 4; ++rg)
          out[(b * EE + e0 + rg) * 4096 + h * 64 + w] = acc[mi][ni][rg] + bov[rg];
      }
    }
  }
}

extern "C" void kernel_launch(void* const* d_in, const int* in_sizes, int n_in,
                              void* d_out, int out_size, void* d_ws, size_t ws_size,
                              hipStream_t stream) {
  const float* x    = (const float*)d_in[0];
  const float* Wqkv = (const float*)d_in[1];
  const float* bqkv = (const float*)d_in[2];
  const float* Wout = (const float*)d_in[3];
  const float* bout = (const float*)d_in[4];
  unsigned short* ws = (unsigned short*)d_ws;   // needs 512 KB (2 x 256 KB prepped weights)
  hipLaunchKernelGGL(prep_weights, dim3(64), dim3(256), 0, stream, Wqkv, Wout, ws);
  hipLaunchKernelGGL(sep_attn_mfma, dim3(BB * HH), dim3(256), 0, stream,
                     x, Wqkv, bqkv, bout, (float*)d_out, ws);
}

// Round 3
// 357.376 us; speedup vs baseline: 1.9529x; 1.0680x over previous
//
#include <hip/hip_runtime.h>

#define BB   32
#define EE   256
#define HH   64
#define WW   64
#define HIDN 256

typedef _Float16 f16x8 __attribute__((ext_vector_type(8)));   // 8 fp16 = 4 VGPR (MFMA A/B frag)
typedef float    f32x4 __attribute__((ext_vector_type(4)));   // MFMA C/D frag

__device__ __forceinline__ unsigned f2h(float f) {
  _Float16 h = (_Float16)f;                       // v_cvt_f16_f32 (RNE)
  return (unsigned)__builtin_bit_cast(unsigned short, h);
}
__device__ __forceinline__ float h2f(unsigned short u) {
  return (float)__builtin_bit_cast(_Float16, u);  // v_cvt_f32_f16
}

// Transposed x tile in LDS: element (w, c) of [64 w][256 c] fp16.
// 16B slot (8 fp16) index within a row is XORed with (w&7) so fixed-c-column
// accesses across w spread over 8 bank-groups. Bijective per row.
__device__ __forceinline__ int xt_idx(int w, int c) {
  return (w << 8) + ((((c >> 3) ^ (w & 7)) << 3) | (c & 7));
}

// ---------------- prep kernel: split Wv / Wout into fp16 hi/lo, fragment-major ----
// Layout: frag index ((mt*8 + ks)*2 + hl)*64 + lane, each frag = 8 fp16 (16B).
// Lane holds W[m = mt*16 + (lane&15)][k = ks*32 + (lane>>4)*8 + i], i=0..7.
__global__ __launch_bounds__(256) void prep_weights(
    const float* __restrict__ Wqkv, const float* __restrict__ Wout,
    unsigned short* __restrict__ ws)
{
  const int t = blockIdx.x * 256 + threadIdx.x;   // 16384 threads total
  const int which = t >> 13;                      // 0 = Wv (qkv rows 257..512), 1 = Wout
  const int r = t & 8191;
  const int m = r >> 5, k8 = r & 31, k0 = k8 * 8;
  const float* src = which ? (Wout + m * HIDN + k0)
                           : (Wqkv + (1 + HIDN + m) * EE + k0);
  unsigned short* dst = ws + which * 131072;      // 256 KB per matrix (hi+lo)
  float4 a = *(const float4*)src;
  float4 bq = *(const float4*)(src + 4);
  float v[8] = {a.x, a.y, a.z, a.w, bq.x, bq.y, bq.z, bq.w};
  const int mt = m >> 4, ks = k8 >> 2, lane = (m & 15) + ((k8 & 3) << 4);
  const int base = ((mt * 8 + ks) * 2) * 64 * 8 + lane * 8;   // hi block; lo at +512
  __align__(16) unsigned short hs[8], ls[8];
  #pragma unroll
  for (int i = 0; i < 8; ++i) {
    unsigned hu = f2h(v[i]);
    hs[i] = (unsigned short)hu;
    ls[i] = (unsigned short)f2h(v[i] - h2f((unsigned short)hu));
  }
  *(uint4*)&dst[base]       = *(const uint4*)hs;
  *(uint4*)&dst[base + 512] = *(const uint4*)ls;
}

// Preload A-fragments (hi+lo) for ks=0 — hoisted early to hide L2 latency.
__device__ __forceinline__ void preload_a(
    const f16x8* __restrict__ Wp, int wid, int lane, f16x8 ah[4], f16x8 al[4])
{
  #pragma unroll
  for (int mi = 0; mi < 4; ++mi) {
    const int fb = ((wid * 4 + mi) * 8) * 2;
    ah[mi] = Wp[fb * 64 + lane];
    al[mi] = Wp[(fb + 1) * 64 + lane];
  }
}

// ---------------- MFMA GEMM: C[256 m][64 w] = W[256 m][256 k] * Xt[k][w] ----------
// 4 waves, wave wid owns m in [wid*64, wid*64+64) as 4 mtiles x 4 ntiles of 16x16.
// W is 2-way fp16 split (hi+lo, near-exact); x single fp16 -> 2 MFMA per tile.
// A-frags software-pipelined (explicit next-ks double buffer); no barriers.
__device__ __forceinline__ void mfma_gemm_f16(
    const f16x8* __restrict__ Wp,
    const unsigned short* __restrict__ Xp,
    const int wid, const int lane,
    f16x8 ah[4], f16x8 al[4],            // preloaded ks=0, clobbered
    f32x4 acc[4][4])
{
  const int l15 = lane & 15;
  const int kb  = (lane >> 4) * 8;
  #pragma unroll
  for (int ks = 0; ks < 8; ++ks) {
    f16x8 ahn[4], aln[4];
    if (ks < 7) {                         // prefetch next-ks A during this ks's MFMAs
      #pragma unroll
      for (int mi = 0; mi < 4; ++mi) {
        const int fb = ((wid * 4 + mi) * 8 + ks + 1) * 2;
        ahn[mi] = Wp[fb * 64 + lane];
        aln[mi] = Wp[(fb + 1) * 64 + lane];
      }
    }
    f16x8 bf[4];
    #pragma unroll
    for (int ni = 0; ni < 4; ++ni)
      bf[ni] = *(const f16x8*)&Xp[xt_idx(ni * 16 + l15, ks * 32 + kb)];
    __builtin_amdgcn_s_setprio(1);
    #pragma unroll
    for (int mi = 0; mi < 4; ++mi) {
      #pragma unroll
      for (int ni = 0; ni < 4; ++ni) {
        acc[mi][ni] = __builtin_amdgcn_mfma_f32_16x16x32_f16(ah[mi], bf[ni], acc[mi][ni], 0, 0, 0);
        acc[mi][ni] = __builtin_amdgcn_mfma_f32_16x16x32_f16(al[mi], bf[ni], acc[mi][ni], 0, 0, 0);
      }
    }
    __builtin_amdgcn_s_setprio(0);
    if (ks < 7) {
      #pragma unroll
      for (int mi = 0; mi < 4; ++mi) { ah[mi] = ahn[mi]; al[mi] = aln[mi]; }
    }
  }
}

// One workgroup = one (b,h) slice, 256 threads = 4 waves.
// LDS ~37.3 KB; launch_bounds(256,3) caps VGPR at 170 -> target 3 blocks/CU.
// (If WRITE_SIZE inflates vs 131 MB, the cap spilled -> fall back to (256,2).)
__global__ __launch_bounds__(256, 3) void sep_attn_mfma(
    const float* __restrict__ x, const float* __restrict__ Wqkv,
    const float* __restrict__ bqkv, const float* __restrict__ bout,
    float* __restrict__ out, const unsigned short* __restrict__ wsp)
{
  __shared__ __align__(16) unsigned short Xh[64 * 256];   // 32 KB: x fp16, then gated fp16
  __shared__ __align__(16) float qpart[256];
  __shared__ __align__(16) float ss[64];
  __shared__ __align__(16) float xbar_s[EE];
  __shared__ __align__(16) float cvs[EE];
  __shared__ __align__(16) float sbv[EE];      // value bias  bqkv[257..512]
  __shared__ __align__(16) float sbout[EE];    // output bias

  const int tid  = threadIdx.x;
  const int lane = tid & 63;
  const int wid  = tid >> 6;
  const int bh = blockIdx.x;
  const int b  = bh >> 6;
  const int h  = bh & 63;
  const int gbase = (b * EE) * 4096 + h * 64;   // x[b,c,h,w] = x[gbase + c*4096 + w]

  // ---- P0: coalesced load + in-register 4x4 shfl-transpose -> LDS fp16 [w][c] ----
  // Lane (c_off = lane>>4, wq = lane&15) loads float4 = X[c][4wq..4wq+3] (rows
  // contiguous across lanes 0-15 -> fully coalesced). Two butterfly stages
  // (xor 16 then xor 32) transpose each 4c x 4w patch; each lane ends with
  // 4 consecutive c at one w -> single ds_write_b64. 16 writes vs 128 scalar.
  {
    sbv[tid]   = bqkv[1 + HIDN + tid];
    sbout[tid] = bout[tid];
    const int wq = lane & 15, c_off = lane >> 4;
    const int sel = c_off & 1, sel2 = c_off >> 1;
    const int wfin = wq * 4 + sel * 2 + sel2;
    #pragma unroll
    for (int it = 0; it < 16; ++it) {
      const int cb = it * 16 + wid * 4;
      const int c  = cb + c_off;
      float4 v = *(const float4*)&x[gbase + c * 4096 + wq * 4];
      unsigned p0 = f2h(v.x) | (f2h(v.y) << 16);   // (w=4wq, 4wq+1) @ my c
      unsigned p1 = f2h(v.z) | (f2h(v.w) << 16);   // (w=4wq+2, 4wq+3) @ my c
      unsigned rA = (unsigned)__shfl_xor((int)p0, 16);
      unsigned rB = (unsigned)__shfl_xor((int)p1, 16);
      unsigned a_src = sel ? rB : p0;
      unsigned b_src = sel ? p1 : rA;
      unsigned d0 = (a_src & 0xffffu) | (b_src << 16);        // c-pair @ w_a
      unsigned d1 = (a_src >> 16) | (b_src & 0xffff0000u);    // c-pair @ w_a+1
      unsigned e0 = (unsigned)__shfl_xor((int)d0, 32);
      unsigned e1 = (unsigned)__shfl_xor((int)d1, 32);
      uint2 qq;
      qq.x = sel2 ? e1 : d0;   // c0,c1 @ wfin
      qq.y = sel2 ? d1 : e0;   // c2,c3 @ wfin
      *(uint2*)&Xh[xt_idx(wfin, cb)] = qq;
    }
  }
  __syncthreads();

  // GEMM1 ks=0 A-frags: issue now, latency hides under P1-P4.
  f16x8 a1h[4], a1l[4];
  preload_a((const f16x8*)wsp, wid, lane, a1h, a1l);

  // ---- P1: query partials from LDS fp16 ----
  {
    const int w = tid & 63, cg = tid >> 6;     // cg wave-uniform -> Wq loads scalar
    const float* wq = Wqkv + cg * 64;
    float q = 0.f;
    #pragma unroll
    for (int f = 0; f < 8; ++f) {
      const int c0 = cg * 64 + f * 8;
      f16x8 hv = *(const f16x8*)&Xh[xt_idx(w, c0)];
      float4 wa = *(const float4*)&wq[f * 8];
      float4 wb = *(const float4*)&wq[f * 8 + 4];
      float wf[8] = {wa.x, wa.y, wa.z, wa.w, wb.x, wb.y, wb.z, wb.w};
      #pragma unroll
      for (int e = 0; e < 8; ++e)
        q = fmaf(wf[e], (float)hv[e], q);
    }
    qpart[tid] = q;                            // tid == cg*64 + w
  }
  __syncthreads();

  // ---- P2: softmax over the 64 w positions (one wave) ----
  if (tid < 64) {
    float q = qpart[tid] + qpart[64 + tid] + qpart[128 + tid] + qpart[192 + tid] + bqkv[0];
    float m = q;
    #pragma unroll
    for (int off = 32; off; off >>= 1) m = fmaxf(m, __shfl_xor(m, off));
    float e = expf(q - m);
    float s = e;
    #pragma unroll
    for (int off = 32; off; off >>= 1) s += __shfl_xor(s, off);
    ss[tid] = e / s;
  }
  __syncthreads();

  // ---- P3: xbar[c] = sum_w score[w] * x[c,w]  (LDS fp16, scalar u16 reads) ----
  {
    const int c = tid;
    float a = 0.f;
    #pragma unroll
    for (int f = 0; f < 16; ++f) {
      float4 sv = *(const float4*)&ss[f * 4];
      float svf[4] = {sv.x, sv.y, sv.z, sv.w};
      #pragma unroll
      for (int j = 0; j < 4; ++j)
        a = fmaf(svf[j], h2f(Xh[xt_idx(f * 4 + j, c)]), a);
    }
    xbar_s[c] = a;
  }
  __syncthreads();

  // ---- P4: cv[c] = Wk_row(c) . xbar + bk[c]  (key GEMM collapsed, fp32) ----
  {
    const int c = tid;
    const float* wk = Wqkv + (1 + c) * EE;
    float a = 0.f;
    #pragma unroll 8
    for (int f = 0; f < 64; ++f) {
      float4 wv = *(const float4*)&wk[f * 4];
      float4 xb = *(const float4*)&xbar_s[f * 4];
      a += wv.x * xb.x + wv.y * xb.y + wv.z * xb.z + wv.w * xb.w;
    }
    cvs[c] = a + bqkv[1 + c];
    // visibility to the gating phase is guaranteed by the post-GEMM1 barrier
  }

  // ---- GEMM1: value = Wv * x ----
  f32x4 acc[4][4];
  #pragma unroll
  for (int mi = 0; mi < 4; ++mi)
    #pragma unroll
    for (int ni = 0; ni < 4; ++ni) {
      acc[mi][ni][0] = 0.f; acc[mi][ni][1] = 0.f;
      acc[mi][ni][2] = 0.f; acc[mi][ni][3] = 0.f;
    }
  mfma_gemm_f16((const f16x8*)wsp, Xh, wid, lane, a1h, a1l, acc);

  // GEMM2 ks=0 A-frags: issue before the barrier, latency hides under gate.
  f16x8 a2h[4], a2l[4];
  preload_a((const f16x8*)(wsp + 131072), wid, lane, a2h, a2l);

  __syncthreads();   // all waves done reading Xh; cvs now visible

  // ---- Gate: relu(value + bv) * cv -> fp16, write transposed into LDS ----
  // D-frag rows are 4 consecutive hid channels per lane -> one b64 store per frag.
  {
    const int l15 = lane & 15, l4 = lane >> 4;
    #pragma unroll
    for (int mi = 0; mi < 4; ++mi) {
      const int c0 = (wid * 4 + mi) * 16 + l4 * 4;
      float4 cv4 = *(const float4*)&cvs[c0];
      float4 bv4 = *(const float4*)&sbv[c0];
      float cvv[4] = {cv4.x, cv4.y, cv4.z, cv4.w};
      float bvv[4] = {bv4.x, bv4.y, bv4.z, bv4.w};
      #pragma unroll
      for (int ni = 0; ni < 4; ++ni) {
        const int w = ni * 16 + l15;
        unsigned hs[4];
        #pragma unroll
        for (int rg = 0; rg < 4; ++rg)
          hs[rg] = f2h(fmaxf(acc[mi][ni][rg] + bvv[rg], 0.f) * cvv[rg]);
        uint2 uh;
        uh.x = hs[0] | (hs[1] << 16);
        uh.y = hs[2] | (hs[3] << 16);
        *(uint2*)&Xh[xt_idx(w, c0)] = uh;
      }
    }
  }
  __syncthreads();

  // ---- GEMM2: out = Wout * gated ----
  #pragma unroll
  for (int mi = 0; mi < 4; ++mi)
    #pragma unroll
    for (int ni = 0; ni < 4; ++ni) {
      acc[mi][ni][0] = 0.f; acc[mi][ni][1] = 0.f;
      acc[mi][ni][2] = 0.f; acc[mi][ni][3] = 0.f;
    }
  mfma_gemm_f16((const f16x8*)(wsp + 131072), Xh, wid, lane, a2h, a2l, acc);

  // ---- Epilogue: bias + store (4x 64B segments per instr -> coalesced) ----
  {
    const int l15 = lane & 15, l4 = lane >> 4;
    #pragma unroll
    for (int mi = 0; mi < 4; ++mi) {
      const int e0 = (wid * 4 + mi) * 16 + l4 * 4;
      float4 bo4 = *(const float4*)&sbout[e0];
      float bov[4] = {bo4.x, bo4.y, bo4.z, bo4.w};
      #pragma unroll
      for (int ni = 0; ni < 4; ++ni) {
        const int w = ni * 16 + l15;
        #pragma unroll
        for (int rg = 0; rg < 4; ++rg)
          out[(b * EE + e0 + rg) * 4096 + h * 64 + w] = acc[mi][ni][rg] + bov[rg];
      }
    }
  }
}

extern "C" void kernel_launch(void* const* d_in, const int* in_sizes, int n_in,
                              void* d_out, int out_size, void* d_ws, size_t ws_size,
                              hipStream_t stream) {
  const float* x    = (const float*)d_in[0];
  const float* Wqkv = (const float*)d_in[1];
  const float* bqkv = (const float*)d_in[2];
  const float* Wout = (const float*)d_in[3];
  const float* bout = (const float*)d_in[4];
  unsigned short* ws = (unsigned short*)d_ws;   // needs 512 KB (2 x 256 KB prepped weights)
  hipLaunchKernelGGL(prep_weights, dim3(64), dim3(256), 0, stream, Wqkv, Wout, ws);
  hipLaunchKernelGGL(sep_attn_mfma, dim3(BB * HH), dim3(256), 0, stream,
                     x, Wqkv, bqkv, bout, (float*)d_out, ws);
}

// Round 5
// 318.236 us; speedup vs baseline: 2.1931x; 1.1230x over previous
//
#include <hip/hip_runtime.h>

#define BB   32
#define EE   256
#define HH   64
#define WW   64
#define HIDN 256

typedef _Float16 f16x8 __attribute__((ext_vector_type(8)));   // 8 fp16 = 4 VGPR (MFMA A/B frag)
typedef float    f32x4 __attribute__((ext_vector_type(4)));   // MFMA C/D frag

__device__ __forceinline__ unsigned f2h(float f) {
  _Float16 h = (_Float16)f;                       // v_cvt_f16_f32 (RNE)
  return (unsigned)__builtin_bit_cast(unsigned short, h);
}
__device__ __forceinline__ float h2f(unsigned short u) {
  return (float)__builtin_bit_cast(_Float16, u);  // v_cvt_f32_f16
}

// Transposed x tile in LDS: element (w, c) of [64 w][256 c] fp16.
// 16B slot (8 fp16) index within a row is XORed with (w&7) so fixed-c-column
// accesses across w spread over 8 bank-groups. Bijective per row.
__device__ __forceinline__ int xt_idx(int w, int c) {
  return (w << 8) + ((((c >> 3) ^ (w & 7)) << 3) | (c & 7));
}

// ---------------- prep kernel: split Wv / Wout into fp16 hi/lo, fragment-major ----
// Layout: frag index ((mt*8 + ks)*2 + hl)*64 + lane, each frag = 8 fp16 (16B).
// Lane holds W[m = mt*16 + (lane&15)][k = ks*32 + (lane>>4)*8 + i], i=0..7.
__global__ __launch_bounds__(256) void prep_weights(
    const float* __restrict__ Wqkv, const float* __restrict__ Wout,
    unsigned short* __restrict__ ws)
{
  const int t = blockIdx.x * 256 + threadIdx.x;   // 16384 threads total
  const int which = t >> 13;                      // 0 = Wv (qkv rows 257..512), 1 = Wout
  const int r = t & 8191;
  const int m = r >> 5, k8 = r & 31, k0 = k8 * 8;
  const float* src = which ? (Wout + m * HIDN + k0)
                           : (Wqkv + (1 + HIDN + m) * EE + k0);
  unsigned short* dst = ws + which * 131072;      // 256 KB per matrix (hi+lo)
  float4 a = *(const float4*)src;
  float4 bq = *(const float4*)(src + 4);
  float v[8] = {a.x, a.y, a.z, a.w, bq.x, bq.y, bq.z, bq.w};
  const int mt = m >> 4, ks = k8 >> 2, lane = (m & 15) + ((k8 & 3) << 4);
  const int base = ((mt * 8 + ks) * 2) * 64 * 8 + lane * 8;   // hi block; lo at +512
  __align__(16) unsigned short hs[8], ls[8];
  #pragma unroll
  for (int i = 0; i < 8; ++i) {
    unsigned hu = f2h(v[i]);
    hs[i] = (unsigned short)hu;
    ls[i] = (unsigned short)f2h(v[i] - h2f((unsigned short)hu));
  }
  *(uint4*)&dst[base]       = *(const uint4*)hs;
  *(uint4*)&dst[base + 512] = *(const uint4*)ls;
}

// Preload A-fragments (hi+lo) for ks=0 — hoisted early to hide L2 latency.
__device__ __forceinline__ void preload_a(
    const f16x8* __restrict__ Wp, int wid, int lane, f16x8 ah[4], f16x8 al[4])
{
  #pragma unroll
  for (int mi = 0; mi < 4; ++mi) {
    const int fb = ((wid * 4 + mi) * 8) * 2;
    ah[mi] = Wp[fb * 64 + lane];
    al[mi] = Wp[(fb + 1) * 64 + lane];
  }
}

// ---------------- MFMA GEMM: C[256 m][64 w] = W[256 m][256 k] * Xt[k][w] ----------
// 4 waves, wave wid owns m in [wid*64, wid*64+64) as 4 mtiles x 4 ntiles of 16x16.
// W is 2-way fp16 split (hi+lo, near-exact); x single fp16 -> 2 MFMA per tile.
// A-frags software-pipelined (explicit next-ks double buffer); no barriers.
__device__ __forceinline__ void mfma_gemm_f16(
    const f16x8* __restrict__ Wp,
    const unsigned short* __restrict__ Xp,
    const int wid, const int lane,
    f16x8 ah[4], f16x8 al[4],            // preloaded ks=0, clobbered
    f32x4 acc[4][4])
{
  const int l15 = lane & 15;
  const int kb  = (lane >> 4) * 8;
  #pragma unroll
  for (int ks = 0; ks < 8; ++ks) {
    f16x8 ahn[4], aln[4];
    if (ks < 7) {                         // prefetch next-ks A during this ks's MFMAs
      #pragma unroll
      for (int mi = 0; mi < 4; ++mi) {
        const int fb = ((wid * 4 + mi) * 8 + ks + 1) * 2;
        ahn[mi] = Wp[fb * 64 + lane];
        aln[mi] = Wp[(fb + 1) * 64 + lane];
      }
    }
    f16x8 bf[4];
    #pragma unroll
    for (int ni = 0; ni < 4; ++ni)
      bf[ni] = *(const f16x8*)&Xp[xt_idx(ni * 16 + l15, ks * 32 + kb)];
    __builtin_amdgcn_s_setprio(1);
    #pragma unroll
    for (int mi = 0; mi < 4; ++mi) {
      #pragma unroll
      for (int ni = 0; ni < 4; ++ni) {
        acc[mi][ni] = __builtin_amdgcn_mfma_f32_16x16x32_f16(ah[mi], bf[ni], acc[mi][ni], 0, 0, 0);
        acc[mi][ni] = __builtin_amdgcn_mfma_f32_16x16x32_f16(al[mi], bf[ni], acc[mi][ni], 0, 0, 0);
      }
    }
    __builtin_amdgcn_s_setprio(0);
    if (ks < 7) {
      #pragma unroll
      for (int mi = 0; mi < 4; ++mi) { ah[mi] = ahn[mi]; al[mi] = aln[mi]; }
    }
  }
}

// One workgroup = one (b,h) slice, 256 threads = 4 waves.
// LDS ~37.5 KB -> 4 blocks/CU possible. launch_bounds(256,2): the (256,3)
// variant made the allocator TARGET 6 waves/EU (VGPR_Count=84 = 512/6) and
// spill the 64-VGPR acc tile to scratch (WRITE_SIZE 131->240 MB, MfmaUtil
// 19->13). (256,2) is the proven-no-spill config (R1: VGPR 124, WRITE 131 MB);
// with fp16 single-B pressure the natural allocation should land <=130, giving
// 3-4 blocks/CU without any spill.
__global__ __launch_bounds__(256, 2) void sep_attn_mfma(
    const float* __restrict__ x, const float* __restrict__ Wqkv,
    const float* __restrict__ bqkv, const float* __restrict__ bout,
    float* __restrict__ out, const unsigned short* __restrict__ wsp)
{
  __shared__ __align__(16) unsigned short Xh[64 * 256];   // 32 KB: x fp16, then gated fp16
  __shared__ __align__(16) float qpart[256];
  __shared__ __align__(16) float ss[64];
  __shared__ __align__(16) float xbar_s[EE];
  __shared__ __align__(16) float cvs[EE];
  __shared__ __align__(16) float sbv[EE];      // value bias  bqkv[257..512]
  __shared__ __align__(16) float sbout[EE];    // output bias

  const int tid  = threadIdx.x;
  const int lane = tid & 63;
  const int wid  = tid >> 6;
  const int bh = blockIdx.x;
  const int b  = bh >> 6;
  const int h  = bh & 63;
  const int gbase = (b * EE) * 4096 + h * 64;   // x[b,c,h,w] = x[gbase + c*4096 + w]

  // ---- P0: coalesced load + in-register 4x4 shfl-transpose -> LDS fp16 [w][c] ----
  // Lane (c_off = lane>>4, wq = lane&15) loads float4 = X[c][4wq..4wq+3] (rows
  // contiguous across lanes 0-15 -> fully coalesced). Two butterfly stages
  // (xor 16 then xor 32) transpose each 4c x 4w patch; each lane ends with
  // 4 consecutive c at one w -> single ds_write_b64. 16 writes vs 128 scalar.
  {
    sbv[tid]   = bqkv[1 + HIDN + tid];
    sbout[tid] = bout[tid];
    const int wq = lane & 15, c_off = lane >> 4;
    const int sel = c_off & 1, sel2 = c_off >> 1;
    const int wfin = wq * 4 + sel * 2 + sel2;
    #pragma unroll
    for (int it = 0; it < 16; ++it) {
      const int cb = it * 16 + wid * 4;
      const int c  = cb + c_off;
      float4 v = *(const float4*)&x[gbase + c * 4096 + wq * 4];
      unsigned p0 = f2h(v.x) | (f2h(v.y) << 16);   // (w=4wq, 4wq+1) @ my c
      unsigned p1 = f2h(v.z) | (f2h(v.w) << 16);   // (w=4wq+2, 4wq+3) @ my c
      unsigned rA = (unsigned)__shfl_xor((int)p0, 16);
      unsigned rB = (unsigned)__shfl_xor((int)p1, 16);
      unsigned a_src = sel ? rB : p0;
      unsigned b_src = sel ? p1 : rA;
      unsigned d0 = (a_src & 0xffffu) | (b_src << 16);        // c-pair @ w_a
      unsigned d1 = (a_src >> 16) | (b_src & 0xffff0000u);    // c-pair @ w_a+1
      unsigned e0 = (unsigned)__shfl_xor((int)d0, 32);
      unsigned e1 = (unsigned)__shfl_xor((int)d1, 32);
      uint2 qq;
      qq.x = sel2 ? e1 : d0;   // c0,c1 @ wfin
      qq.y = sel2 ? d1 : e0;   // c2,c3 @ wfin
      *(uint2*)&Xh[xt_idx(wfin, cb)] = qq;
    }
  }
  __syncthreads();

  // GEMM1 ks=0 A-frags: issue now, latency hides under P1-P4.
  f16x8 a1h[4], a1l[4];
  preload_a((const f16x8*)wsp, wid, lane, a1h, a1l);

  // ---- P1: query partials from LDS fp16 ----
  {
    const int w = tid & 63, cg = tid >> 6;     // cg wave-uniform -> Wq loads scalar
    const float* wq = Wqkv + cg * 64;
    float q = 0.f;
    #pragma unroll
    for (int f = 0; f < 8; ++f) {
      const int c0 = cg * 64 + f * 8;
      f16x8 hv = *(const f16x8*)&Xh[xt_idx(w, c0)];
      float4 wa = *(const float4*)&wq[f * 8];
      float4 wb = *(const float4*)&wq[f * 8 + 4];
      float wf[8] = {wa.x, wa.y, wa.z, wa.w, wb.x, wb.y, wb.z, wb.w};
      #pragma unroll
      for (int e = 0; e < 8; ++e)
        q = fmaf(wf[e], (float)hv[e], q);
    }
    qpart[tid] = q;                            // tid == cg*64 + w
  }
  __syncthreads();

  // ---- P2: softmax over the 64 w positions (one wave) ----
  if (tid < 64) {
    float q = qpart[tid] + qpart[64 + tid] + qpart[128 + tid] + qpart[192 + tid] + bqkv[0];
    float m = q;
    #pragma unroll
    for (int off = 32; off; off >>= 1) m = fmaxf(m, __shfl_xor(m, off));
    float e = expf(q - m);
    float s = e;
    #pragma unroll
    for (int off = 32; off; off >>= 1) s += __shfl_xor(s, off);
    ss[tid] = e / s;
  }
  __syncthreads();

  // ---- P3: xbar[c] = sum_w score[w] * x[c,w]  (LDS fp16, scalar u16 reads) ----
  {
    const int c = tid;
    float a = 0.f;
    #pragma unroll
    for (int f = 0; f < 16; ++f) {
      float4 sv = *(const float4*)&ss[f * 4];
      float svf[4] = {sv.x, sv.y, sv.z, sv.w};
      #pragma unroll
      for (int j = 0; j < 4; ++j)
        a = fmaf(svf[j], h2f(Xh[xt_idx(f * 4 + j, c)]), a);
    }
    xbar_s[c] = a;
  }
  __syncthreads();

  // ---- P4: cv[c] = Wk_row(c) . xbar + bk[c]  (key GEMM collapsed, fp32) ----
  {
    const int c = tid;
    const float* wk = Wqkv + (1 + c) * EE;
    float a = 0.f;
    #pragma unroll 8
    for (int f = 0; f < 64; ++f) {
      float4 wv = *(const float4*)&wk[f * 4];
      float4 xb = *(const float4*)&xbar_s[f * 4];
      a += wv.x * xb.x + wv.y * xb.y + wv.z * xb.z + wv.w * xb.w;
    }
    cvs[c] = a + bqkv[1 + c];
    // visibility to the gating phase is guaranteed by the post-GEMM1 barrier
  }

  // ---- GEMM1: value = Wv * x ----
  f32x4 acc[4][4];
  #pragma unroll
  for (int mi = 0; mi < 4; ++mi)
    #pragma unroll
    for (int ni = 0; ni < 4; ++ni) {
      acc[mi][ni][0] = 0.f; acc[mi][ni][1] = 0.f;
      acc[mi][ni][2] = 0.f; acc[mi][ni][3] = 0.f;
    }
  mfma_gemm_f16((const f16x8*)wsp, Xh, wid, lane, a1h, a1l, acc);

  // GEMM2 ks=0 A-frags: issue before the barrier, latency hides under gate.
  f16x8 a2h[4], a2l[4];
  preload_a((const f16x8*)(wsp + 131072), wid, lane, a2h, a2l);

  __syncthreads();   // all waves done reading Xh; cvs now visible

  // ---- Gate: relu(value + bv) * cv -> fp16, write transposed into LDS ----
  // D-frag rows are 4 consecutive hid channels per lane -> one b64 store per frag.
  {
    const int l15 = lane & 15, l4 = lane >> 4;
    #pragma unroll
    for (int mi = 0; mi < 4; ++mi) {
      const int c0 = (wid * 4 + mi) * 16 + l4 * 4;
      float4 cv4 = *(const float4*)&cvs[c0];
      float4 bv4 = *(const float4*)&sbv[c0];
      float cvv[4] = {cv4.x, cv4.y, cv4.z, cv4.w};
      float bvv[4] = {bv4.x, bv4.y, bv4.z, bv4.w};
      #pragma unroll
      for (int ni = 0; ni < 4; ++ni) {
        const int w = ni * 16 + l15;
        unsigned hs[4];
        #pragma unroll
        for (int rg = 0; rg < 4; ++rg)
          hs[rg] = f2h(fmaxf(acc[mi][ni][rg] + bvv[rg], 0.f) * cvv[rg]);
        uint2 uh;
        uh.x = hs[0] | (hs[1] << 16);
        uh.y = hs[2] | (hs[3] << 16);
        *(uint2*)&Xh[xt_idx(w, c0)] = uh;
      }
    }
  }
  __syncthreads();

  // ---- GEMM2: out = Wout * gated ----
  #pragma unroll
  for (int mi = 0; mi < 4; ++mi)
    #pragma unroll
    for (int ni = 0; ni < 4; ++ni) {
      acc[mi][ni][0] = 0.f; acc[mi][ni][1] = 0.f;
      acc[mi][ni][2] = 0.f; acc[mi][ni][3] = 0.f;
    }
  mfma_gemm_f16((const f16x8*)(wsp + 131072), Xh, wid, lane, a2h, a2l, acc);

  // ---- Epilogue: bias + store (4x 64B segments per instr -> coalesced) ----
  {
    const int l15 = lane & 15, l4 = lane >> 4;
    #pragma unroll
    for (int mi = 0; mi < 4; ++mi) {
      const int e0 = (wid * 4 + mi) * 16 + l4 * 4;
      float4 bo4 = *(const float4*)&sbout[e0];
      float bov[4] = {bo4.x, bo4.y, bo4.z, bo4.w};
      #pragma unroll
      for (int ni = 0; ni < 4; ++ni) {
        const int w = ni * 16 + l15;
        #pragma unroll
        for (int rg = 0; rg < 4; ++rg)
          out[(b * EE + e0 + rg) * 4096 + h * 64 + w] = acc[mi][ni][rg] + bov[rg];
      }
    }
  }
}

extern "C" void kernel_launch(void* const* d_in, const int* in_sizes, int n_in,
                              void* d_out, int out_size, void* d_ws, size_t ws_size,
                              hipStream_t stream) {
  const float* x    = (const float*)d_in[0];
  const float* Wqkv = (const float*)d_in[1];
  const float* bqkv = (const float*)d_in[2];
  const float* Wout = (const float*)d_in[3];
  const float* bout = (const float*)d_in[4];
  unsigned short* ws = (unsigned short*)d_ws;   // needs 512 KB (2 x 256 KB prepped weights)
  hipLaunchKernelGGL(prep_weights, dim3(64), dim3(256), 0, stream, Wqkv, Wout, ws);
  hipLaunchKernelGGL(sep_attn_mfma, dim3(BB * HH), dim3(256), 0, stream,
                     x, Wqkv, bqkv, bout, (float*)d_out, ws);
}